// Round 1
// baseline (403.134 us; speedup 1.0000x reference)
//
#include <hip/hip_runtime.h>

typedef __bf16 bf16_t;
typedef bf16_t bf16x8 __attribute__((ext_vector_type(8)));
typedef float floatx4 __attribute__((ext_vector_type(4)));

#define L1C 512
#define L2C 512
#define BC  32
#define DC  1024
#define KTOP 256
#define NPAIR (L1C * L2C)   // 262144 pairs per batch

__device__ __forceinline__ unsigned short f2bf(float f) {
    unsigned u = __float_as_uint(f);
    u += 0x7FFFu + ((u >> 16) & 1u);   // RNE (data has no NaNs)
    return (unsigned short)(u >> 16);
}

// ---------------- cast f32 -> bf16 (x4 vectorized) ----------------
__global__ void cast_bf16_kernel(const float* __restrict__ src,
                                 unsigned short* __restrict__ dst, int n4) {
    int i = blockIdx.x * blockDim.x + threadIdx.x;
    if (i < n4) {
        float4 v = reinterpret_cast<const float4*>(src)[i];
        ushort4 o;
        o.x = f2bf(v.x); o.y = f2bf(v.y); o.z = f2bf(v.z); o.w = f2bf(v.w);
        reinterpret_cast<ushort4*>(dst)[i] = o;
    }
}

// ---------------- W[d][e] -> Wt[e][d], bf16 ----------------
__global__ void transpose_cast_kernel(const float* __restrict__ W,
                                      unsigned short* __restrict__ Wt) {
    __shared__ float tile[32][33];
    int d0 = blockIdx.x * 32, e0 = blockIdx.y * 32;
    int tx = threadIdx.x;
    for (int i = threadIdx.y; i < 32; i += 8)
        tile[i][tx] = W[(size_t)(d0 + i) * DC + e0 + tx];
    __syncthreads();
    for (int i = threadIdx.y; i < 32; i += 8)
        Wt[(size_t)(e0 + i) * DC + d0 + tx] = f2bf(tile[tx][i]);
}

// ---------------- GEMM1: T[r][e] = sum_d A1[r][d] * Wt[e][d], bf16 out ----
// M=16384 N=1024 K=1024, both operands K-contiguous (BT-GEMM).
__global__ __launch_bounds__(256) void gemm1_kernel(
    const unsigned short* __restrict__ A,    // [16384,1024] bf16
    const unsigned short* __restrict__ Bt,   // [1024,1024]  bf16 (Wt)
    unsigned short* __restrict__ C) {        // [16384,1024] bf16
    __shared__ unsigned short As[128][32];
    __shared__ unsigned short Bs[128][32];
    int tid = threadIdx.x;
    int wave = tid >> 6, lane = tid & 63;
    int lane15 = lane & 15, quad = lane >> 4;
    int wm = wave >> 1, wn = wave & 1;
    size_t m0 = (size_t)blockIdx.x * 128, n0 = (size_t)blockIdx.y * 128;

    floatx4 zero = {0.f, 0.f, 0.f, 0.f};
    floatx4 acc[4][4];
#pragma unroll
    for (int i = 0; i < 4; i++)
#pragma unroll
        for (int j = 0; j < 4; j++) acc[i][j] = zero;

    for (int k0 = 0; k0 < DC; k0 += 32) {
#pragma unroll
        for (int c = 0; c < 2; c++) {
            int cid = c * 256 + tid;
            int row = cid >> 2, col8 = (cid & 3) * 8;
            *reinterpret_cast<int4*>(&As[row][col8]) =
                *reinterpret_cast<const int4*>(&A[(m0 + row) * DC + k0 + col8]);
            *reinterpret_cast<int4*>(&Bs[row][col8]) =
                *reinterpret_cast<const int4*>(&Bt[(n0 + row) * DC + k0 + col8]);
        }
        __syncthreads();
        bf16x8 af[4], bfr[4];
#pragma unroll
        for (int mi = 0; mi < 4; mi++)
            af[mi] = *reinterpret_cast<const bf16x8*>(&As[wm * 64 + mi * 16 + lane15][quad * 8]);
#pragma unroll
        for (int ni = 0; ni < 4; ni++)
            bfr[ni] = *reinterpret_cast<const bf16x8*>(&Bs[wn * 64 + ni * 16 + lane15][quad * 8]);
#pragma unroll
        for (int mi = 0; mi < 4; mi++)
#pragma unroll
            for (int ni = 0; ni < 4; ni++)
                acc[mi][ni] = __builtin_amdgcn_mfma_f32_16x16x32_bf16(
                    af[mi], bfr[ni], acc[mi][ni], 0, 0, 0);
        __syncthreads();
    }
#pragma unroll
    for (int mi = 0; mi < 4; mi++)
#pragma unroll
        for (int ni = 0; ni < 4; ni++)
#pragma unroll
            for (int r = 0; r < 4; r++) {
                size_t row = m0 + wm * 64 + mi * 16 + quad * 4 + r;
                size_t col = n0 + wn * 64 + ni * 16 + lane15;
                C[row * DC + col] = f2bf(acc[mi][ni][r]);
            }
}

// ---------------- GEMM2 per batch: S = relu(T_b @ H2_b^T + bias) -> keys ---
// A rows: T[i*32+b][:], B rows: H2[j*32+b][:]  (row stride 32*DC each)
__global__ __launch_bounds__(256) void gemm2_kernel(
    const unsigned short* __restrict__ Tm,   // [16384,1024] bf16
    const unsigned short* __restrict__ H2,   // [16384,1024] bf16 (inputs2 layout)
    const int* __restrict__ mask1, const int* __restrict__ mask2,
    const float* __restrict__ bptr,
    unsigned* __restrict__ keys) {           // [32][512][512] u32 monotone keys
    __shared__ unsigned short As[128][32];
    __shared__ unsigned short Bs[128][32];
    int tid = threadIdx.x;
    int wave = tid >> 6, lane = tid & 63;
    int lane15 = lane & 15, quad = lane >> 4;
    int wm = wave >> 1, wn = wave & 1;
    int m0 = blockIdx.x * 128, n0 = blockIdx.y * 128;
    int b = blockIdx.z;
    const size_t ldr = (size_t)BC * DC;      // 32768 row stride
    const unsigned short* Ab = Tm + (size_t)b * DC;
    const unsigned short* Bb = H2 + (size_t)b * DC;

    floatx4 zero = {0.f, 0.f, 0.f, 0.f};
    floatx4 acc[4][4];
#pragma unroll
    for (int i = 0; i < 4; i++)
#pragma unroll
        for (int j = 0; j < 4; j++) acc[i][j] = zero;

    for (int k0 = 0; k0 < DC; k0 += 32) {
#pragma unroll
        for (int c = 0; c < 2; c++) {
            int cid = c * 256 + tid;
            int row = cid >> 2, col8 = (cid & 3) * 8;
            *reinterpret_cast<int4*>(&As[row][col8]) =
                *reinterpret_cast<const int4*>(&Ab[(size_t)(m0 + row) * ldr + k0 + col8]);
            *reinterpret_cast<int4*>(&Bs[row][col8]) =
                *reinterpret_cast<const int4*>(&Bb[(size_t)(n0 + row) * ldr + k0 + col8]);
        }
        __syncthreads();
        bf16x8 af[4], bfr[4];
#pragma unroll
        for (int mi = 0; mi < 4; mi++)
            af[mi] = *reinterpret_cast<const bf16x8*>(&As[wm * 64 + mi * 16 + lane15][quad * 8]);
#pragma unroll
        for (int ni = 0; ni < 4; ni++)
            bfr[ni] = *reinterpret_cast<const bf16x8*>(&Bs[wn * 64 + ni * 16 + lane15][quad * 8]);
#pragma unroll
        for (int mi = 0; mi < 4; mi++)
#pragma unroll
            for (int ni = 0; ni < 4; ni++)
                acc[mi][ni] = __builtin_amdgcn_mfma_f32_16x16x32_bf16(
                    af[mi], bfr[ni], acc[mi][ni], 0, 0, 0);
        __syncthreads();
    }

    float bias = bptr[0];
    bool v1[16];
#pragma unroll
    for (int mi = 0; mi < 4; mi++)
#pragma unroll
        for (int r = 0; r < 4; r++) {
            int i = m0 + wm * 64 + mi * 16 + quad * 4 + r;
            v1[mi * 4 + r] = (mask1[i * BC + b] == 0);
        }
#pragma unroll
    for (int ni = 0; ni < 4; ni++) {
        int j = n0 + wn * 64 + ni * 16 + lane15;
        bool v2 = (mask2[j * BC + b] == 0);
#pragma unroll
        for (int mi = 0; mi < 4; mi++)
#pragma unroll
            for (int r = 0; r < 4; r++) {
                int i = m0 + wm * 64 + mi * 16 + quad * 4 + r;
                float s = acc[mi][ni][r] + bias;
                s = s > 0.f ? s : 0.f;
                unsigned key = (v2 && v1[mi * 4 + r])
                                   ? (__float_as_uint(s) | 0x80000000u) : 0u;
                keys[(size_t)b * NPAIR + (size_t)i * L2C + j] = key;
            }
    }
}

// ---------------- top-k radix select machinery ----------------
__global__ void topk_init_kernel(unsigned* ghist, unsigned* prefix,
                                 unsigned* kneed, unsigned* ccount) {
    int b = blockIdx.x, t = threadIdx.x;
    ghist[b * 256 + t] = 0;
    if (t == 0) { prefix[b] = 0; kneed[b] = KTOP; ccount[b] = 0; }
}

// grid (16, 32): each block scans 16384 keys of batch blockIdx.y
__global__ void hist_kernel(const unsigned* __restrict__ keys,
                            const unsigned* __restrict__ prefix,
                            unsigned* __restrict__ ghist,
                            int shift, unsigned himask) {
    __shared__ unsigned h[256];
    int t = threadIdx.x, b = blockIdx.y;
    h[t] = 0;
    __syncthreads();
    unsigned pv = prefix[b];
    const uint4* kv = reinterpret_cast<const uint4*>(keys + (size_t)b * NPAIR)
                      + (size_t)blockIdx.x * 4096;
#pragma unroll 4
    for (int i = 0; i < 16; i++) {
        uint4 kk = kv[i * 256 + t];
        if ((kk.x & himask) == pv) atomicAdd(&h[(kk.x >> shift) & 255u], 1u);
        if ((kk.y & himask) == pv) atomicAdd(&h[(kk.y >> shift) & 255u], 1u);
        if ((kk.z & himask) == pv) atomicAdd(&h[(kk.z >> shift) & 255u], 1u);
        if ((kk.w & himask) == pv) atomicAdd(&h[(kk.w >> shift) & 255u], 1u);
    }
    __syncthreads();
    if (h[t]) atomicAdd(&ghist[b * 256 + t], h[t]);
}

__global__ void select_kernel(unsigned* __restrict__ ghist,
                              unsigned* __restrict__ prefix,
                              unsigned* __restrict__ kneed, int shift) {
    __shared__ unsigned sh[256];
    int t = threadIdx.x, b = blockIdx.x;
    sh[t] = ghist[b * 256 + t];
    __syncthreads();
    ghist[b * 256 + t] = 0;   // ready for next pass
    if (t == 0) {
        unsigned kn = kneed[b], c = 0, pv = prefix[b];
        for (int bin = 255; bin >= 0; --bin) {
            unsigned hc = sh[bin];
            if (c + hc >= kn) {
                pv |= ((unsigned)bin) << shift;
                kn -= c;
                break;
            }
            c += hc;
        }
        prefix[b] = pv;
        kneed[b] = kn;
    }
}

// grid (16, 32): gather keys strictly greater than threshold
__global__ void gather_kernel(const unsigned* __restrict__ keys,
                              const unsigned* __restrict__ prefix,
                              unsigned* __restrict__ cand,
                              unsigned* __restrict__ ccount) {
    int t = threadIdx.x, b = blockIdx.y;
    unsigned T = prefix[b];
    const uint4* kv = reinterpret_cast<const uint4*>(keys + (size_t)b * NPAIR)
                      + (size_t)blockIdx.x * 4096;
#pragma unroll 4
    for (int i = 0; i < 16; i++) {
        uint4 kk = kv[i * 256 + t];
        unsigned v[4] = {kk.x, kk.y, kk.z, kk.w};
#pragma unroll
        for (int c = 0; c < 4; c++) {
            if (v[c] > T) {
                unsigned p = atomicAdd(&ccount[b], 1u);
                if (p < KTOP) cand[b * KTOP + p] = v[c];
            }
        }
    }
}

__device__ __forceinline__ float decode_key(unsigned k) {
    return __uint_as_float(k & 0x7FFFFFFFu);
}

// 32 blocks x 256: bitonic sort candidates descending, backfill, emit
__global__ void sort_out_kernel(const unsigned* __restrict__ cand,
                                const unsigned* __restrict__ ccount,
                                const unsigned* __restrict__ prefix,
                                const unsigned* __restrict__ kneed,
                                float* __restrict__ out) {
    __shared__ unsigned sh[256];
    int t = threadIdx.x, b = blockIdx.x;
    unsigned cg = ccount[b];
    if (cg > KTOP) cg = KTOP;
    sh[t] = (t < (int)cg) ? cand[b * KTOP + t] : 0u;
    __syncthreads();
#pragma unroll
    for (int k2 = 2; k2 <= 256; k2 <<= 1) {
#pragma unroll
        for (int j2 = k2 >> 1; j2 > 0; j2 >>= 1) {
            int ixj = t ^ j2;
            if (ixj > t) {
                unsigned a = sh[t], c = sh[ixj];
                bool up = (t & k2) == 0;
                if (up ? (a < c) : (a > c)) { sh[t] = c; sh[ixj] = a; }
            }
            __syncthreads();
        }
    }
    unsigned T = prefix[b];
    float fill;
    if (T >= 0x80000000u) fill = decode_key(T);
    else fill = (cg > 0) ? decode_key(sh[cg - 1]) : -__builtin_inff();
    out[b * KTOP + t] = (t < (int)cg) ? decode_key(sh[t]) : fill;
}

// ---------------- launch ----------------
extern "C" void kernel_launch(void* const* d_in, const int* in_sizes, int n_in,
                              void* d_out, int out_size, void* d_ws, size_t ws_size,
                              hipStream_t stream) {
    const float* in1   = (const float*)d_in[0];   // [512,32,1024]
    const float* in2   = (const float*)d_in[1];   // [512,32,1024]
    const int*   mask1 = (const int*)d_in[2];     // [512,32]
    const int*   mask2 = (const int*)d_in[3];     // [512,32]
    const float* W     = (const float*)d_in[4];   // [1024,1024]
    const float* bias  = (const float*)d_in[5];   // [1]
    float* out = (float*)d_out;

    char* ws = (char*)d_ws;
    size_t off = 0;
    const size_t nElem = (size_t)L1C * BC * DC;       // 16777216
    unsigned short* A1 = (unsigned short*)(ws + off); off += nElem * 2;       // 32 MB
    unsigned short* A2 = (unsigned short*)(ws + off); off += nElem * 2;       // 32 MB
    unsigned short* Wt = (unsigned short*)(ws + off); off += (size_t)DC * DC * 2; // 2 MB
    unsigned short* Tm = (unsigned short*)(ws + off); off += nElem * 2;       // 32 MB
    unsigned* keys   = (unsigned*)(ws + off); off += (size_t)BC * NPAIR * 4;  // 32 MB
    unsigned* ghist  = (unsigned*)(ws + off); off += (size_t)BC * 256 * 4;
    unsigned* prefix = (unsigned*)(ws + off); off += BC * 4;
    unsigned* kneed  = (unsigned*)(ws + off); off += BC * 4;
    unsigned* cand   = (unsigned*)(ws + off); off += (size_t)BC * KTOP * 4;
    unsigned* ccount = (unsigned*)(ws + off); off += BC * 4;

    // 1) casts
    int n4 = (int)(nElem / 4);
    cast_bf16_kernel<<<n4 / 256, 256, 0, stream>>>(in1, A1, n4);
    cast_bf16_kernel<<<n4 / 256, 256, 0, stream>>>(in2, A2, n4);
    transpose_cast_kernel<<<dim3(DC / 32, DC / 32), dim3(32, 8), 0, stream>>>(W, Wt);

    // 2) T = A1 @ Wt^T
    gemm1_kernel<<<dim3(128, 8), 256, 0, stream>>>(A1, Wt, Tm);

    // 3) per-batch S keys
    gemm2_kernel<<<dim3(4, 4, BC), 256, 0, stream>>>(Tm, A2, mask1, mask2, bias, keys);

    // 4) top-k: 4-pass radix select
    topk_init_kernel<<<BC, 256, 0, stream>>>(ghist, prefix, kneed, ccount);
    const int shifts[4]      = {24, 16, 8, 0};
    const unsigned himasks[4] = {0u, 0xFF000000u, 0xFFFF0000u, 0xFFFFFF00u};
    for (int p = 0; p < 4; p++) {
        hist_kernel<<<dim3(16, BC), 256, 0, stream>>>(keys, prefix, ghist,
                                                      shifts[p], himasks[p]);
        select_kernel<<<BC, 256, 0, stream>>>(ghist, prefix, kneed, shifts[p]);
    }
    gather_kernel<<<dim3(16, BC), 256, 0, stream>>>(keys, prefix, cand, ccount);
    sort_out_kernel<<<BC, 256, 0, stream>>>(cand, ccount, prefix, kneed, out);
}

// Round 2
// 356.730 us; speedup vs baseline: 1.1301x; 1.1301x over previous
//
#include <hip/hip_runtime.h>

typedef __bf16 bf16_t;
typedef bf16_t bf16x8 __attribute__((ext_vector_type(8)));
typedef float floatx4 __attribute__((ext_vector_type(4)));

#define L1C 512
#define L2C 512
#define BC  32
#define DC  1024
#define KTOP 256
#define NPAIR (L1C * L2C)   // 262144 pairs per batch
#define NBIN 4096           // 12-bit histogram (sign+exp+3 mantissa bits)
#define CAND_MAX 16384

__device__ __forceinline__ unsigned short f2bf(float f) {
    unsigned u = __float_as_uint(f);
    u += 0x7FFFu + ((u >> 16) & 1u);   // RNE (data has no NaNs)
    return (unsigned short)(u >> 16);
}

// async global->LDS, 16B per lane; LDS dest = wave-uniform base + lane*16
__device__ __forceinline__ void g2l16(const unsigned short* g, unsigned short* l) {
    __builtin_amdgcn_global_load_lds((const unsigned int*)g, (unsigned int*)l,
                                     16, 0, 0);
}

// ---------------- cast f32 -> bf16 (x4 vectorized) ----------------
__global__ void cast_bf16_kernel(const float* __restrict__ src,
                                 unsigned short* __restrict__ dst, int n4) {
    int i = blockIdx.x * blockDim.x + threadIdx.x;
    if (i < n4) {
        float4 v = reinterpret_cast<const float4*>(src)[i];
        ushort4 o;
        o.x = f2bf(v.x); o.y = f2bf(v.y); o.z = f2bf(v.z); o.w = f2bf(v.w);
        reinterpret_cast<ushort4*>(dst)[i] = o;
    }
}

// ---------------- W[d][e] -> Wt[e][d], bf16 ----------------
__global__ void transpose_cast_kernel(const float* __restrict__ W,
                                      unsigned short* __restrict__ Wt) {
    __shared__ float tile[32][33];
    int d0 = blockIdx.x * 32, e0 = blockIdx.y * 32;
    int tx = threadIdx.x;
    for (int i = threadIdx.y; i < 32; i += 8)
        tile[i][tx] = W[(size_t)(d0 + i) * DC + e0 + tx];
    __syncthreads();
    for (int i = threadIdx.y; i < 32; i += 8)
        Wt[(size_t)(e0 + i) * DC + d0 + tx] = f2bf(tile[tx][i]);
}

// ---------------- zero per-batch histograms + counters ----------------
__global__ void init_kernel(unsigned* __restrict__ ghist,
                            unsigned* __restrict__ ccount) {
    int gid = blockIdx.x * blockDim.x + threadIdx.x;
    if (gid < BC * NBIN) ghist[gid] = 0;
    if (gid < BC) ccount[gid] = 0;
}

// ---------------- GEMM1: T[r][e] = sum_d A1[r][d] * Wt[e][d], bf16 out ----
// M=16384 N=1024 K=1024, both operands K-contiguous (BT-GEMM), m97 staging.
__global__ __launch_bounds__(256) void gemm1_kernel(
    const unsigned short* __restrict__ A,    // [16384,1024] bf16
    const unsigned short* __restrict__ Bt,   // [1024,1024]  bf16 (Wt)
    unsigned short* __restrict__ C) {        // [16384,1024] bf16
    __shared__ unsigned short As[128][32];
    __shared__ unsigned short Bs[128][32];
    int tid = threadIdx.x;
    int wave = tid >> 6, lane = tid & 63;
    int lane15 = lane & 15, quad = lane >> 4;
    int wm = wave >> 1, wn = wave & 1;
    size_t m0 = (size_t)blockIdx.x * 128, n0 = (size_t)blockIdx.y * 128;

    floatx4 zero = {0.f, 0.f, 0.f, 0.f};
    floatx4 acc[4][4];
#pragma unroll
    for (int i = 0; i < 4; i++)
#pragma unroll
        for (int j = 0; j < 4; j++) acc[i][j] = zero;

    for (int k0 = 0; k0 < DC; k0 += 32) {
#pragma unroll
        for (int c = 0; c < 2; c++) {
            int cid = c * 256 + tid;
            int row = cid >> 2, col8 = (cid & 3) * 8;
            unsigned short* lbase = &As[0][0] + (c * 256 + wave * 64) * 8;
            g2l16(&A[(m0 + row) * DC + k0 + col8], lbase);
            unsigned short* lbase2 = &Bs[0][0] + (c * 256 + wave * 64) * 8;
            g2l16(&Bt[(n0 + row) * DC + k0 + col8], lbase2);
        }
        __syncthreads();
        bf16x8 af[4], bfr[4];
#pragma unroll
        for (int mi = 0; mi < 4; mi++)
            af[mi] = *reinterpret_cast<const bf16x8*>(&As[wm * 64 + mi * 16 + lane15][quad * 8]);
#pragma unroll
        for (int ni = 0; ni < 4; ni++)
            bfr[ni] = *reinterpret_cast<const bf16x8*>(&Bs[wn * 64 + ni * 16 + lane15][quad * 8]);
#pragma unroll
        for (int mi = 0; mi < 4; mi++)
#pragma unroll
            for (int ni = 0; ni < 4; ni++)
                acc[mi][ni] = __builtin_amdgcn_mfma_f32_16x16x32_bf16(
                    af[mi], bfr[ni], acc[mi][ni], 0, 0, 0);
        __syncthreads();
    }
#pragma unroll
    for (int mi = 0; mi < 4; mi++)
#pragma unroll
        for (int ni = 0; ni < 4; ni++)
#pragma unroll
            for (int r = 0; r < 4; r++) {
                size_t row = m0 + wm * 64 + mi * 16 + quad * 4 + r;
                size_t col = n0 + wn * 64 + ni * 16 + lane15;
                C[row * DC + col] = f2bf(acc[mi][ni][r]);
            }
}

// ---------------- GEMM2: S = relu(T_b @ H2_b^T + bias) -> keys + hist ----
__global__ __launch_bounds__(256) void gemm2_kernel(
    const unsigned short* __restrict__ Tm,   // [16384,1024] bf16
    const unsigned short* __restrict__ H2,   // [16384,1024] bf16 (inputs2 layout)
    const int* __restrict__ mask1, const int* __restrict__ mask2,
    const float* __restrict__ bptr,
    unsigned* __restrict__ keys,             // [32][512][512] u32 monotone keys
    unsigned* __restrict__ ghist) {          // [32][4096]
    __shared__ unsigned short As[128][32];
    __shared__ unsigned short Bs[128][32];
    __shared__ unsigned lh[NBIN];
    int tid = threadIdx.x;
    int wave = tid >> 6, lane = tid & 63;
    int lane15 = lane & 15, quad = lane >> 4;
    int wm = wave >> 1, wn = wave & 1;
    int m0 = blockIdx.x * 128, n0 = blockIdx.y * 128;
    int b = blockIdx.z;
    const size_t ldr = (size_t)BC * DC;      // 32768 row stride
    const unsigned short* Ab = Tm + (size_t)b * DC;
    const unsigned short* Bb = H2 + (size_t)b * DC;

    for (int i = tid; i < NBIN; i += 256) lh[i] = 0;

    floatx4 zero = {0.f, 0.f, 0.f, 0.f};
    floatx4 acc[4][4];
#pragma unroll
    for (int i = 0; i < 4; i++)
#pragma unroll
        for (int j = 0; j < 4; j++) acc[i][j] = zero;

    for (int k0 = 0; k0 < DC; k0 += 32) {
#pragma unroll
        for (int c = 0; c < 2; c++) {
            int cid = c * 256 + tid;
            int row = cid >> 2, col8 = (cid & 3) * 8;
            unsigned short* lbase = &As[0][0] + (c * 256 + wave * 64) * 8;
            g2l16(&Ab[(size_t)(m0 + row) * ldr + k0 + col8], lbase);
            unsigned short* lbase2 = &Bs[0][0] + (c * 256 + wave * 64) * 8;
            g2l16(&Bb[(size_t)(n0 + row) * ldr + k0 + col8], lbase2);
        }
        __syncthreads();
        bf16x8 af[4], bfr[4];
#pragma unroll
        for (int mi = 0; mi < 4; mi++)
            af[mi] = *reinterpret_cast<const bf16x8*>(&As[wm * 64 + mi * 16 + lane15][quad * 8]);
#pragma unroll
        for (int ni = 0; ni < 4; ni++)
            bfr[ni] = *reinterpret_cast<const bf16x8*>(&Bs[wn * 64 + ni * 16 + lane15][quad * 8]);
#pragma unroll
        for (int mi = 0; mi < 4; mi++)
#pragma unroll
            for (int ni = 0; ni < 4; ni++)
                acc[mi][ni] = __builtin_amdgcn_mfma_f32_16x16x32_bf16(
                    af[mi], bfr[ni], acc[mi][ni], 0, 0, 0);
        __syncthreads();
    }

    float bias = bptr[0];
    bool v1[16];
#pragma unroll
    for (int mi = 0; mi < 4; mi++)
#pragma unroll
        for (int r = 0; r < 4; r++) {
            int i = m0 + wm * 64 + mi * 16 + quad * 4 + r;
            v1[mi * 4 + r] = (mask1[i * BC + b] == 0);
        }
#pragma unroll
    for (int ni = 0; ni < 4; ni++) {
        int j = n0 + wn * 64 + ni * 16 + lane15;
        bool v2 = (mask2[j * BC + b] == 0);
#pragma unroll
        for (int mi = 0; mi < 4; mi++)
#pragma unroll
            for (int r = 0; r < 4; r++) {
                int i = m0 + wm * 64 + mi * 16 + quad * 4 + r;
                float s = acc[mi][ni][r] + bias;
                s = s > 0.f ? s : 0.f;
                unsigned key = (v2 && v1[mi * 4 + r])
                                   ? (__float_as_uint(s) | 0x80000000u) : 0u;
                keys[(size_t)b * NPAIR + (size_t)i * L2C + j] = key;
                atomicAdd(&lh[key >> 20], 1u);
            }
    }
    __syncthreads();
    for (int i = tid; i < NBIN; i += 256)
        if (lh[i]) atomicAdd(&ghist[b * NBIN + i], lh[i]);
}

// ---------------- pick threshold bin from 4096-bin hist (1 block/batch) ----
__global__ void select_kernel(const unsigned* __restrict__ ghist,
                              unsigned* __restrict__ prefix) {
    __shared__ unsigned h[NBIN];
    __shared__ unsigned csum[256];
    int b = blockIdx.x, t = threadIdx.x;
    for (int i = t; i < NBIN; i += 256) h[i] = ghist[b * NBIN + i];
    __syncthreads();
    unsigned s = 0;
#pragma unroll
    for (int i = 0; i < 16; i++) s += h[t * 16 + i];
    csum[t] = s;
    __syncthreads();
    if (t == 0) {
        unsigned cum = 0;
        int chunk = -1;
        for (int c = 255; c >= 128; --c) {       // bins >= 2048 only (valid keys)
            if (cum + csum[c] >= KTOP) { chunk = c; break; }
            cum += csum[c];
        }
        unsigned threshbin = 2048;               // fewer than k valid: take all
        if (chunk >= 0) {
            for (int bin = chunk * 16 + 15; bin >= chunk * 16; --bin) {
                if (cum + h[bin] >= KTOP) { threshbin = (unsigned)bin; break; }
                cum += h[bin];
            }
        }
        prefix[b] = threshbin << 20;
    }
}

// ---------------- gather all keys >= threshold ----------------
__global__ void gather_kernel(const unsigned* __restrict__ keys,
                              const unsigned* __restrict__ prefix,
                              unsigned* __restrict__ cand,
                              unsigned* __restrict__ ccount) {
    int t = threadIdx.x, b = blockIdx.y;
    unsigned T = prefix[b];
    const uint4* kv = reinterpret_cast<const uint4*>(keys + (size_t)b * NPAIR)
                      + (size_t)blockIdx.x * 4096;
#pragma unroll 4
    for (int i = 0; i < 16; i++) {
        uint4 kk = kv[i * 256 + t];
        unsigned v[4] = {kk.x, kk.y, kk.z, kk.w};
#pragma unroll
        for (int c = 0; c < 4; c++) {
            if (v[c] >= T) {
                unsigned p = atomicAdd(&ccount[b], 1u);
                if (p < CAND_MAX) cand[b * CAND_MAX + p] = v[c];
            }
        }
    }
}

__device__ __forceinline__ float decode_key(unsigned k) {
    return __uint_as_float(k & 0x7FFFFFFFu);
}

// ---------------- per-batch: bitonic-sort candidates desc, emit top-256 ----
__global__ void final_kernel(const unsigned* __restrict__ cand,
                             const unsigned* __restrict__ ccount,
                             float* __restrict__ out) {
    __shared__ unsigned sh[CAND_MAX];
    int b = blockIdx.x, t = threadIdx.x;
    unsigned cc = ccount[b];
    if (cc > CAND_MAX) cc = CAND_MAX;
    int n = 256;
    while (n < (int)cc) n <<= 1;
    for (int i = t; i < n; i += 256)
        sh[i] = (i < (int)cc) ? cand[b * CAND_MAX + i] : 0u;
    __syncthreads();
    for (int k2 = 2; k2 <= n; k2 <<= 1) {
        for (int j2 = k2 >> 1; j2 > 0; j2 >>= 1) {
            for (int idx = t; idx < n; idx += 256) {
                int ixj = idx ^ j2;
                if (ixj > idx) {
                    unsigned a = sh[idx], c = sh[ixj];
                    bool up = (idx & k2) == 0;
                    if (up ? (a < c) : (a > c)) { sh[idx] = c; sh[ixj] = a; }
                }
            }
            __syncthreads();
        }
    }
    int nval = (int)cc < KTOP ? (int)cc : KTOP;
    float fill = nval > 0 ? decode_key(sh[nval - 1]) : -__builtin_inff();
    out[b * KTOP + t] = (t < nval) ? decode_key(sh[t]) : fill;
}

// ---------------- launch ----------------
extern "C" void kernel_launch(void* const* d_in, const int* in_sizes, int n_in,
                              void* d_out, int out_size, void* d_ws, size_t ws_size,
                              hipStream_t stream) {
    const float* in1   = (const float*)d_in[0];   // [512,32,1024]
    const float* in2   = (const float*)d_in[1];   // [512,32,1024]
    const int*   mask1 = (const int*)d_in[2];     // [512,32]
    const int*   mask2 = (const int*)d_in[3];     // [512,32]
    const float* W     = (const float*)d_in[4];   // [1024,1024]
    const float* bias  = (const float*)d_in[5];   // [1]
    float* out = (float*)d_out;

    char* ws = (char*)d_ws;
    size_t off = 0;
    const size_t nElem = (size_t)L1C * BC * DC;       // 16777216
    unsigned short* A1 = (unsigned short*)(ws + off); off += nElem * 2;       // 32 MB
    unsigned short* A2 = (unsigned short*)(ws + off); off += nElem * 2;       // 32 MB
    unsigned short* Wt = (unsigned short*)(ws + off); off += (size_t)DC * DC * 2; // 2 MB
    unsigned short* Tm = (unsigned short*)(ws + off); off += nElem * 2;       // 32 MB
    unsigned* keys   = (unsigned*)(ws + off); off += (size_t)BC * NPAIR * 4;  // 32 MB
    unsigned* ghist  = (unsigned*)(ws + off); off += (size_t)BC * NBIN * 4;   // 512 KB
    unsigned* prefix = (unsigned*)(ws + off); off += BC * 4;
    unsigned* cand   = (unsigned*)(ws + off); off += (size_t)BC * CAND_MAX * 4; // 2 MB
    unsigned* ccount = (unsigned*)(ws + off); off += BC * 4;

    int n4 = (int)(nElem / 4);
    cast_bf16_kernel<<<n4 / 256, 256, 0, stream>>>(in1, A1, n4);
    cast_bf16_kernel<<<n4 / 256, 256, 0, stream>>>(in2, A2, n4);
    transpose_cast_kernel<<<dim3(DC / 32, DC / 32), dim3(32, 8), 0, stream>>>(W, Wt);
    init_kernel<<<(BC * NBIN) / 256, 256, 0, stream>>>(ghist, ccount);

    gemm1_kernel<<<dim3(128, 8), 256, 0, stream>>>(A1, Wt, Tm);
    gemm2_kernel<<<dim3(4, 4, BC), 256, 0, stream>>>(Tm, A2, mask1, mask2, bias,
                                                     keys, ghist);

    select_kernel<<<BC, 256, 0, stream>>>(ghist, prefix);
    gather_kernel<<<dim3(16, BC), 256, 0, stream>>>(keys, prefix, cand, ccount);
    final_kernel<<<BC, 256, 0, stream>>>(cand, ccount, out);
}